// Round 14
// baseline (284.656 us; speedup 1.0000x reference)
//
#include <hip/hip_runtime.h>
#include <math.h>

#define D_ 512
#define H_ 8
#define DFF_ 2048
#define SLOTS_ 1024
#define TOPK_ 5
#define NCAND_ 8
#define NTOK_ 8192
#define SEQ_ 1024
#define LN_EPS_ 1e-5f

typedef __attribute__((ext_vector_type(8))) short bf16x8;
typedef __attribute__((ext_vector_type(4))) float f32x4;
typedef __attribute__((ext_vector_type(4))) unsigned u32x4;
typedef unsigned short u16;

// split fp32 -> bf16 hi + bf16 lo (truncation; rem captured to ~2^-16 rel)
__device__ inline void split2(float x, unsigned short& hi, unsigned short& lo) {
    unsigned u = __builtin_bit_cast(unsigned, x);
    hi = (unsigned short)(u >> 16);
    float h = __builtin_bit_cast(float, u & 0xFFFF0000u);
    float rem = x - h;
    lo = (unsigned short)(__builtin_bit_cast(unsigned, rem) >> 16);
}

__device__ __forceinline__ void gld16(const void* g, void* l) {
    __builtin_amdgcn_global_load_lds(
        (const __attribute__((address_space(1))) void*)g,
        (__attribute__((address_space(3))) void*)l, 16, 0, 0);
}

__device__ __forceinline__ int SW7(int r) { return (r ^ (r >> 3)) & 7; }
__device__ __forceinline__ const bf16x8* frag(const unsigned short* p, int r, int c) {
    return (const bf16x8*)(p + r * 64 + ((c ^ SW7(r)) << 3));
}

// ---------------------------------------------------------------- prep: weight splits + mn + LN1
__global__ __launch_bounds__(256) void prep_kernel(
    const float* __restrict__ inw, const float* __restrict__ outw,
    const float* __restrict__ w1, const float* __restrict__ w2,
    const float* __restrict__ mem, const float* __restrict__ src,
    const float* __restrict__ ln1g, const float* __restrict__ ln1b,
    u16* __restrict__ inwh, u16* __restrict__ inwl,
    u16* __restrict__ outwh, u16* __restrict__ outwl,
    u16* __restrict__ w1h, u16* __restrict__ w2h,
    float* __restrict__ mn, u16* __restrict__ mnh, u16* __restrict__ mnl,
    u16* __restrict__ hh, u16* __restrict__ hl)
{
    const int bid = blockIdx.x;
    const int t = threadIdx.x;
    if (bid < 3072) {
        const int i = (bid * 256 + t) * 4;
        const float* x;
        u16 *hhp, *llp;
        int base;
        if (i < 786432)       { x = inw;  hhp = inwh;  llp = inwl;  base = 0; }
        else if (i < 1048576) { x = outw; hhp = outwh; llp = outwl; base = 786432; }
        else if (i < 2097152) { x = w1;   hhp = w1h;   llp = nullptr; base = 1048576; }
        else                  { x = w2;   hhp = w2h;   llp = nullptr; base = 2097152; }
        const int j = i - base;
        const float4 v = *(const float4*)(x + j);
        const float vv[4] = {v.x, v.y, v.z, v.w};
        u16 h[4], l[4];
#pragma unroll
        for (int e = 0; e < 4; ++e) split2(vv[e], h[e], l[e]);
        hhp[j + 0] = h[0]; hhp[j + 1] = h[1]; hhp[j + 2] = h[2]; hhp[j + 3] = h[3];
        if (llp) { llp[j + 0] = l[0]; llp[j + 1] = l[1]; llp[j + 2] = l[2]; llp[j + 3] = l[3]; }
    } else if (bid < 3328) {
        const int row = (bid - 3072) * 4 + (t >> 6);
        const int lane = t & 63;
        float v[8];
        float ss = 0.0f;
#pragma unroll
        for (int j = 0; j < 8; ++j) {
            v[j] = mem[(size_t)row * D_ + j * 64 + lane];
            ss += v[j] * v[j];
        }
#pragma unroll
        for (int off = 32; off; off >>= 1) ss += __shfl_xor(ss, off);
        const float inv = 1.0f / fmaxf(sqrtf(ss), 1e-12f);
#pragma unroll
        for (int j = 0; j < 8; ++j) {
            const float y = v[j] * inv;
            mn[(size_t)row * D_ + j * 64 + lane] = y;
            u16 h, l;
            split2(y, h, l);
            mnh[(size_t)row * D_ + j * 64 + lane] = h;
            mnl[(size_t)row * D_ + j * 64 + lane] = l;
        }
    } else {
        const int row = bid - 3328;
        const float a = src[(size_t)row * D_ + t];
        const float b = src[(size_t)row * D_ + t + 256];
        float s = a + b;
        float ss = a * a + b * b;
#pragma unroll
        for (int off = 32; off; off >>= 1) {
            s += __shfl_xor(s, off);
            ss += __shfl_xor(ss, off);
        }
        __shared__ float rs[4], rss[4];
        if ((t & 63) == 0) { rs[t >> 6] = s; rss[t >> 6] = ss; }
        __syncthreads();
        s = rs[0] + rs[1] + rs[2] + rs[3];
        ss = rss[0] + rss[1] + rss[2] + rss[3];
        const float mu = s * (1.0f / D_);
        const float var = ss * (1.0f / D_) - mu * mu;
        const float r = rsqrtf(var + LN_EPS_);
        const float y0 = (a - mu) * r * ln1g[t] + ln1b[t];
        const float y1 = (b - mu) * r * ln1g[t + 256] + ln1b[t + 256];
        u16 h0, l0, h1, l1;
        split2(y0, h0, l0);
        split2(y1, h1, l1);
        hh[(size_t)row * D_ + t] = h0;
        hh[(size_t)row * D_ + t + 256] = h1;
        hl[(size_t)row * D_ + t] = l0;
        hl[(size_t)row * D_ + t + 256] = l1;
    }
}

// ------------------------------------------------- MFMA GEMM (NT), 128x128 tile
enum { EP_QKV = 0, EP_OUTPROJ = 1, EP_SIM = 2, EP_FFN1 = 3, EP_FFN2 = 4 };

template <int SPLIT, int MODE>
__global__ __launch_bounds__(256) void gemm_mf(
    const unsigned short* __restrict__ Ahg, const unsigned short* __restrict__ Alg,
    const unsigned short* __restrict__ Bhg, const unsigned short* __restrict__ Blg,
    const float* __restrict__ bias, const float* __restrict__ res,
    float* __restrict__ C,
    unsigned short* __restrict__ Ch, unsigned short* __restrict__ Cl,
    int M, int N, int K)
{
    __shared__ __align__(16) unsigned short sm[(SPLIT == 3 ? 4 : 2) * 8192];
    unsigned short* Ah = sm;
    unsigned short* Al = sm + 8192;
    unsigned short* Bh = sm + (SPLIT == 3 ? 16384 : 8192);
    unsigned short* Bl = sm + 24576;

    const int tid = threadIdx.x;
    const int lane = tid & 63;
    const int w = tid >> 6;
    const int wr = w >> 1, wc = w & 1;
    const int g = lane >> 4, ln = lane & 15;
    const int m0 = blockIdx.x * 128, n0 = blockIdx.y * 128;
    const int lrow8 = lane >> 3, lchunk = lane & 7;

    const unsigned short* gsrc;
    unsigned short* lds;
    int rbase, rofs, nblk;
    if (SPLIT == 3) {
        nblk = 16; rofs = 0;
        if (w == 0)      { gsrc = Ahg; lds = Ah; rbase = m0; }
        else if (w == 1) { gsrc = Alg; lds = Al; rbase = m0; }
        else if (w == 2) { gsrc = Bhg; lds = Bh; rbase = n0; }
        else             { gsrc = Blg; lds = Bl; rbase = n0; }
    } else {
        nblk = 8; rofs = (w & 1) * 64;
        if (w < 2) { gsrc = Ahg; lds = Ah; rbase = m0; }
        else       { gsrc = Bhg; lds = Bh; rbase = n0; }
    }

    f32x4 acc[4][4];
#pragma unroll
    for (int i = 0; i < 4; ++i)
#pragma unroll
        for (int j = 0; j < 4; ++j) acc[i][j] = (f32x4){0.f, 0.f, 0.f, 0.f};

    for (int k0 = 0; k0 < K; k0 += 64) {
#pragma unroll
        for (int blk = 0; blk < nblk; ++blk) {
            const int row = rofs + blk * 8 + lrow8;
            const int sc = lchunk ^ SW7(row);
            gld16(gsrc + (size_t)(rbase + row) * K + k0 + sc * 8,
                  lds + (rofs + blk * 8) * 64);
        }
        __syncthreads();

#pragma unroll
        for (int ks = 0; ks < 2; ++ks) {
            bf16x8 a_h[4], a_l[4], b_h[4], b_l[4];
#pragma unroll
            for (int mi = 0; mi < 4; ++mi) {
                a_h[mi] = *frag(Ah, wr * 64 + mi * 16 + ln, ks * 4 + g);
                if (SPLIT == 3) a_l[mi] = *frag(Al, wr * 64 + mi * 16 + ln, ks * 4 + g);
            }
#pragma unroll
            for (int ni = 0; ni < 4; ++ni) {
                b_h[ni] = *frag(Bh, wc * 64 + ni * 16 + ln, ks * 4 + g);
                if (SPLIT == 3) b_l[ni] = *frag(Bl, wc * 64 + ni * 16 + ln, ks * 4 + g);
            }
#pragma unroll
            for (int mi = 0; mi < 4; ++mi)
#pragma unroll
                for (int ni = 0; ni < 4; ++ni) {
                    acc[mi][ni] = __builtin_amdgcn_mfma_f32_16x16x32_bf16(
                        a_h[mi], b_h[ni], acc[mi][ni], 0, 0, 0);
                    if (SPLIT == 3) {
                        acc[mi][ni] = __builtin_amdgcn_mfma_f32_16x16x32_bf16(
                            a_h[mi], b_l[ni], acc[mi][ni], 0, 0, 0);
                        acc[mi][ni] = __builtin_amdgcn_mfma_f32_16x16x32_bf16(
                            a_l[mi], b_h[ni], acc[mi][ni], 0, 0, 0);
                    }
                }
        }
        __syncthreads();
    }

#pragma unroll
    for (int mi = 0; mi < 4; ++mi) {
#pragma unroll
        for (int ni = 0; ni < 4; ++ni) {
            const int gn = n0 + wc * 64 + ni * 16 + ln;
            const float bz = (MODE == EP_SIM) ? 0.0f : bias[gn];
#pragma unroll
            for (int r2 = 0; r2 < 4; ++r2) {
                const int gm = m0 + wr * 64 + mi * 16 + g * 4 + r2;
                float v = acc[mi][ni][r2];
                if (MODE == EP_SIM) {
                    unsigned short h16, l16;
                    split2(v, h16, l16);
                    Ch[(size_t)gm * N + gn] = h16;
                } else if (MODE == EP_QKV) {
                    v += bz;
                    if (gn < D_) v *= 0.125f;     // fold 1/sqrt(DH) into Q
                    unsigned short h16, l16;
                    split2(v, h16, l16);
                    Ch[(size_t)gm * N + gn] = h16;
                    Cl[(size_t)gm * N + gn] = l16;
                } else if (MODE == EP_OUTPROJ) {
                    v += bz + res[(size_t)gm * N + gn];
                    C[(size_t)gm * N + gn] = v;
                    unsigned short h16, l16;
                    split2(v, h16, l16);
                    Ch[(size_t)gm * N + gn] = h16;
                } else if (MODE == EP_FFN1) {
                    v += bz;
                    v = 0.5f * v * (1.0f + erff(v * 0.70710678118654752f));
                    unsigned short h16, l16;
                    split2(v, h16, l16);
                    Ch[(size_t)gm * N + gn] = h16;
                } else {   // EP_FFN2
                    v += bz + res[(size_t)gm * N + gn];
                    C[(size_t)gm * N + gn] = v;
                }
            }
        }
    }
}

// ------------------------------------------------- flash attention, MFMA bf16x3
__global__ __launch_bounds__(256, 2) void attn_kernel(
    const unsigned short* __restrict__ qkvh, const unsigned short* __restrict__ qkvl,
    unsigned short* __restrict__ ctxh, unsigned short* __restrict__ ctxl)
{
    const int id = blockIdx.x;          // 0..511
    const int bh = id & 63;
    const int qt = id >> 6;             // 0..7
    const int b = bh >> 3, h = bh & 7;
    const int tok0 = b * SEQ_ + qt * 128;
    const int kbase0 = b * SEQ_;
    const int tid = threadIdx.x;
    const int lane = tid & 63;
    const int w = tid >> 6;             // wave: 32 q-rows
    const int ln = lane & 15, g = lane >> 4;
    const int lrow8 = lane >> 3, lchunk = lane & 7;

    __shared__ __align__(16) unsigned char smb[65536];
    unsigned*       PP  = (unsigned*)smb;
    unsigned short* Qh  = (unsigned short*)smb;
    unsigned short* Ql  = (unsigned short*)(smb + 16384);
    unsigned short* Kh  = (unsigned short*)(smb + 32768);
    unsigned short* Kl  = (unsigned short*)(smb + 40960);
    unsigned short* Vth = (unsigned short*)(smb + 49152);
    unsigned short* Vtl = (unsigned short*)(smb + 57344);

    const int qoff = h * 64, koff = 512 + h * 64, voff = 1024 + h * 64;

    // ---- stage Q (pre-scaled), hoist fragments
#pragma unroll
    for (int blk = 0; blk < 4; ++blk) {
        const int row = w * 32 + blk * 8 + lrow8;
        const int sc = lchunk ^ SW7(row);
        gld16(qkvh + (size_t)(tok0 + row) * 1536 + qoff + sc * 8,
              Qh + (w * 32 + blk * 8) * 64);
        gld16(qkvl + (size_t)(tok0 + row) * 1536 + qoff + sc * 8,
              Ql + (w * 32 + blk * 8) * 64);
    }
    __syncthreads();
    bf16x8 qfh[2][2], qfl[2][2];
#pragma unroll
    for (int qi = 0; qi < 2; ++qi)
#pragma unroll
        for (int ks = 0; ks < 2; ++ks) {
            qfh[qi][ks] = *frag(Qh, w * 32 + qi * 16 + ln, ks * 4 + g);
            qfl[qi][ks] = *frag(Ql, w * 32 + qi * 16 + ln, ks * 4 + g);
        }
    __syncthreads();   // Q reads done before PP reused for P

    f32x4 o[4][2];      // O^T[d-tile di][q-tile qi]
#pragma unroll
    for (int di = 0; di < 4; ++di)
#pragma unroll
        for (int qi = 0; qi < 2; ++qi) o[di][qi] = (f32x4){0.f, 0.f, 0.f, 0.f};
    float mrow2[2] = {-INFINITY, -INFINITY};
    float lrow2[2] = {0.f, 0.f};

    // V staging partition: consecutive lanes -> consecutive d-chunks (coalesced)
    const int dc = tid & 7, p2 = tid >> 3;

    for (int kt = 0; kt < 16; ++kt) {
        const int kb2 = kbase0 + kt * 64;
        // ---- stage K
#pragma unroll
        for (int blk = 0; blk < 2; ++blk) {
            const int row = w * 16 + blk * 8 + lrow8;
            const int sc = lchunk ^ SW7(row);
            gld16(qkvh + (size_t)(kb2 + row) * 1536 + koff + sc * 8,
                  Kh + (w * 16 + blk * 8) * 64);
            gld16(qkvl + (size_t)(kb2 + row) * 1536 + koff + sc * 8,
                  Kl + (w * 16 + blk * 8) * 64);
        }
        // ---- stage V transposed (swizzled, packed b32)
        {
            const size_t b0 = (size_t)(kb2 + 2 * p2) * 1536 + voff + dc * 8;
            const bf16x8 h0 = *(const bf16x8*)(qkvh + b0);
            const bf16x8 h1 = *(const bf16x8*)(qkvh + b0 + 1536);
            const bf16x8 l0 = *(const bf16x8*)(qkvl + b0);
            const bf16x8 l1 = *(const bf16x8*)(qkvl + b0 + 1536);
#pragma unroll
            for (int j = 0; j < 8; ++j) {
                const int d = dc * 8 + j;
                const int idx = d * 64 + (((p2 >> 2) ^ SW7(d)) << 3) + ((p2 & 3) << 1);
                *(unsigned*)&Vth[idx] = (unsigned)(unsigned short)h0[j]
                                      | ((unsigned)(unsigned short)h1[j] << 16);
                *(unsigned*)&Vtl[idx] = (unsigned)(unsigned short)l0[j]
                                      | ((unsigned)(unsigned short)l1[j] << 16);
            }
        }
        __syncthreads();

        // ---- S^T = K Q^T (bf16x3): s[ki][qi], row=k (g*4+r2), col=q (ln)
        f32x4 s[4][2];
#pragma unroll
        for (int ki = 0; ki < 4; ++ki)
#pragma unroll
            for (int qi = 0; qi < 2; ++qi) s[ki][qi] = (f32x4){0.f, 0.f, 0.f, 0.f};
        __builtin_amdgcn_s_setprio(1);
#pragma unroll
        for (int ks = 0; ks < 2; ++ks) {
            bf16x8 kbh[4], kbl[4];
#pragma unroll
            for (int ki = 0; ki < 4; ++ki) {
                kbh[ki] = *frag(Kh, ki * 16 + ln, ks * 4 + g);
                kbl[ki] = *frag(Kl, ki * 16 + ln, ks * 4 + g);
            }
#pragma unroll
            for (int ki = 0; ki < 4; ++ki)
#pragma unroll
                for (int qi = 0; qi < 2; ++qi) {
                    s[ki][qi] = __builtin_amdgcn_mfma_f32_16x16x32_bf16(kbh[ki], qfh[qi][ks], s[ki][qi], 0, 0, 0);
                    s[ki][qi] = __builtin_amdgcn_mfma_f32_16x16x32_bf16(kbh[ki], qfl[qi][ks], s[ki][qi], 0, 0, 0);
                    s[ki][qi] = __builtin_amdgcn_mfma_f32_16x16x32_bf16(kbl[ki], qfh[qi][ks], s[ki][qi], 0, 0, 0);
                }
        }
        __builtin_amdgcn_s_setprio(0);

        // ---- online softmax: lane holds 16 k-values per qi for query q=qi*16+ln
        float tm2[2], alpha2[2], psum2[2];
#pragma unroll
        for (int qi = 0; qi < 2; ++qi) {
            float m01 = fmaxf(fmaxf(s[0][qi][0], s[0][qi][1]), fmaxf(s[0][qi][2], s[0][qi][3]));
            float m23 = fmaxf(fmaxf(s[1][qi][0], s[1][qi][1]), fmaxf(s[1][qi][2], s[1][qi][3]));
            float m45 = fmaxf(fmaxf(s[2][qi][0], s[2][qi][1]), fmaxf(s[2][qi][2], s[2][qi][3]));
            float m67 = fmaxf(fmaxf(s[3][qi][0], s[3][qi][1]), fmaxf(s[3][qi][2], s[3][qi][3]));
            tm2[qi] = fmaxf(fmaxf(m01, m23), fmaxf(m45, m67));
        }
#pragma unroll
        for (int qi = 0; qi < 2; ++qi) {
            tm2[qi] = fmaxf(tm2[qi], __shfl_xor(tm2[qi], 16));
            tm2[qi] = fmaxf(tm2[qi], __shfl_xor(tm2[qi], 32));
            const float mnew = fmaxf(mrow2[qi], tm2[qi]);
            alpha2[qi] = __expf(mrow2[qi] - mnew);
            mrow2[qi] = mnew;
            psum2[qi] = 0.f;
        }
        // P = exp(S^T - m): pack (h|l<<16); chunk (ki*4+g) ^ (ln&7) -> conflict-free
#pragma unroll
        for (int qi = 0; qi < 2; ++qi)
#pragma unroll
            for (int ki = 0; ki < 4; ++ki) {
                u32x4 pv;
#pragma unroll
                for (int r2 = 0; r2 < 4; ++r2) {
                    const float p = __expf(s[ki][qi][r2] - mrow2[qi]);
                    psum2[qi] += p;
                    unsigned short h16, l16;
                    split2(p, h16, l16);
                    pv[r2] = (unsigned)h16 | ((unsigned)l16 << 16);
                }
                *(u32x4*)&PP[(w * 32 + qi * 16 + ln) * 64 + (((ki * 4 + g) ^ (ln & 7)) << 2)] = pv;
            }
#pragma unroll
        for (int qi = 0; qi < 2; ++qi) {
            psum2[qi] += __shfl_xor(psum2[qi], 16);
            psum2[qi] += __shfl_xor(psum2[qi], 32);
            lrow2[qi] = lrow2[qi] * alpha2[qi] + psum2[qi];
        }
#pragma unroll
        for (int di = 0; di < 4; ++di)
#pragma unroll
            for (int qi = 0; qi < 2; ++qi)
#pragma unroll
                for (int r2 = 0; r2 < 4; ++r2)
                    o[di][qi][r2] *= alpha2[qi];

        // ---- O^T += Vt P^T (bf16x3)
        __builtin_amdgcn_s_setprio(1);
#pragma unroll
        for (int ks = 0; ks < 2; ++ks) {
            bf16x8 pah[2], pal[2];
#pragma unroll
            for (int qi = 0; qi < 2; ++qi) {
                const unsigned* rowp = PP + (w * 32 + qi * 16 + ln) * 64;
                const int c0 = (2 * ks + (g >> 1)) * 4 + (g & 1) * 2;
                const u32x4 q0 = *(const u32x4*)(rowp + (((c0    ) ^ (ln & 7)) << 2));
                const u32x4 q1 = *(const u32x4*)(rowp + (((c0 + 1) ^ (ln & 7)) << 2));
                u32x4 hu, lu;
                hu[0] = __builtin_amdgcn_perm(q0[1], q0[0], 0x05040100u);
                hu[1] = __builtin_amdgcn_perm(q0[3], q0[2], 0x05040100u);
                hu[2] = __builtin_amdgcn_perm(q1[1], q1[0], 0x05040100u);
                hu[3] = __builtin_amdgcn_perm(q1[3], q1[2], 0x05040100u);
                lu[0] = __builtin_amdgcn_perm(q0[1], q0[0], 0x07060302u);
                lu[1] = __builtin_amdgcn_perm(q0[3], q0[2], 0x07060302u);
                lu[2] = __builtin_amdgcn_perm(q1[1], q1[0], 0x07060302u);
                lu[3] = __builtin_amdgcn_perm(q1[3], q1[2], 0x07060302u);
                pah[qi] = __builtin_bit_cast(bf16x8, hu);
                pal[qi] = __builtin_bit_cast(bf16x8, lu);
            }
            bf16x8 vbh[4], vbl[4];
#pragma unroll
            for (int di = 0; di < 4; ++di) {
                vbh[di] = *frag(Vth, di * 16 + ln, ks * 4 + g);
                vbl[di] = *frag(Vtl, di * 16 + ln, ks * 4 + g);
            }
#pragma unroll
            for (int di = 0; di < 4; ++di)
#pragma unroll
                for (int qi = 0; qi < 2; ++qi) {
                    o[di][qi] = __builtin_amdgcn_mfma_f32_16x16x32_bf16(vbh[di], pah[qi], o[di][qi], 0, 0, 0);
                    o[di][qi] = __builtin_amdgcn_mfma_f32_16x16x32_bf16(vbh[di], pal[qi], o[di][qi], 0, 0, 0);
                    o[di][qi] = __builtin_amdgcn_mfma_f32_16x16x32_bf16(vbl[di], pah[qi], o[di][qi], 0, 0, 0);
                }
        }
        __builtin_amdgcn_s_setprio(0);
        __syncthreads();   // PV done before next staging overwrites K/V
    }

    // ---- epilogue: O^T -> wave-private LDS transpose (reuse PP) -> coalesced stores
#pragma unroll
    for (int di = 0; di < 4; ++di)
#pragma unroll
        for (int qi = 0; qi < 2; ++qi) {
            const float inv = 1.0f / lrow2[qi];
            u32x4 tv;
#pragma unroll
            for (int r2 = 0; r2 < 4; ++r2) {
                const float v = o[di][qi][r2] * inv;
                unsigned short h16, l16;
                split2(v, h16, l16);
                tv[r2] = (unsigned)h16 | ((unsigned)l16 << 16);
            }
            *(u32x4*)&PP[(w * 32 + qi * 16 + ln) * 64 + (((di * 4 + g) ^ (ln & 7)) << 2)] = tv;
        }
    __syncthreads();
    {
        const int qrow = lane >> 1, halfd = lane & 1;
        const unsigned* rowp = PP + (w * 32 + qrow) * 64;
        const size_t gbase = (size_t)(tok0 + w * 32 + qrow) * D_ + h * 64;
#pragma unroll
        for (int gi = 0; gi < 2; ++gi) {
            const int di = halfd * 2 + gi;
#pragma unroll
            for (int pr = 0; pr < 2; ++pr) {
                const int c = di * 4 + pr * 2;
                const u32x4 t0 = *(const u32x4*)(rowp + (((c    ) ^ (qrow & 7)) << 2));
                const u32x4 t1 = *(const u32x4*)(rowp + (((c + 1) ^ (qrow & 7)) << 2));
                u32x4 hv, lv;
                hv[0] = __builtin_amdgcn_perm(t0[1], t0[0], 0x05040100u);
                hv[1] = __builtin_amdgcn_perm(t0[3], t0[2], 0x05040100u);
                hv[2] = __builtin_amdgcn_perm(t1[1], t1[0], 0x05040100u);
                hv[3] = __builtin_amdgcn_perm(t1[3], t1[2], 0x05040100u);
                lv[0] = __builtin_amdgcn_perm(t0[1], t0[0], 0x07060302u);
                lv[1] = __builtin_amdgcn_perm(t0[3], t0[2], 0x07060302u);
                lv[2] = __builtin_amdgcn_perm(t1[1], t1[0], 0x07060302u);
                lv[3] = __builtin_amdgcn_perm(t1[3], t1[2], 0x07060302u);
                *(u32x4*)(ctxh + gbase + di * 16 + pr * 8) = hv;
                *(u32x4*)(ctxl + gbase + di * 16 + pr * 8) = lv;
            }
        }
    }
}

// ---- top-8 -> fp32 refine -> top-5 + softmax + gather + residual + fused LN2
// sim scan vectorized: lane reads 16 contiguous bf16 (2 x b128); idx = lane*16+e
__global__ __launch_bounds__(256) void topk_kernel(
    const u16* __restrict__ sim, const float* __restrict__ src2,
    const float* __restrict__ mn, const float* __restrict__ mem,
    const float* __restrict__ rs_ptr, const float* __restrict__ g2,
    const float* __restrict__ b2, float* __restrict__ out,
    unsigned short* __restrict__ h2h)
{
    const int row = blockIdx.x * 4 + (threadIdx.x >> 6);
    const int lane = threadIdx.x & 63;
    float v[16];
    {
        const bf16x8 s0 = *(const bf16x8*)(sim + (size_t)row * SLOTS_ + lane * 16);
        const bf16x8 s1 = *(const bf16x8*)(sim + (size_t)row * SLOTS_ + lane * 16 + 8);
#pragma unroll
        for (int e = 0; e < 8; ++e) {
            v[e]     = __builtin_bit_cast(float, (unsigned)(unsigned short)s0[e] << 16);
            v[e + 8] = __builtin_bit_cast(float, (unsigned)(unsigned short)s1[e] << 16);
        }
    }

    int ci[NCAND_];
#pragma unroll
    for (int t = 0; t < NCAND_; ++t) {
        float bv = -INFINITY;
        int bi = 0x7fffffff;
#pragma unroll
        for (int j = 0; j < 16; ++j) {
            const int idx = lane * 16 + j;
            if (v[j] > bv || (v[j] == bv && idx < bi)) { bv = v[j]; bi = idx; }
        }
#pragma unroll
        for (int off = 32; off; off >>= 1) {
            const float ov = __shfl_xor(bv, off);
            const int oi = __shfl_xor(bi, off);
            if (ov > bv || (ov == bv && oi < bi)) { bv = ov; bi = oi; }
        }
        ci[t] = bi;
        if (bi >= lane * 16 && bi < lane * 16 + 16) v[bi - lane * 16] = -INFINITY;
    }

    float x[8];
    float ss = 0.0f;
#pragma unroll
    for (int j = 0; j < 8; ++j) {
        x[j] = src2[(size_t)row * D_ + j * 64 + lane];
        ss += x[j] * x[j];
    }
#pragma unroll
    for (int off = 32; off; off >>= 1) ss += __shfl_xor(ss, off);
    const float invn = 1.0f / fmaxf(sqrtf(ss), 1e-12f);

    float rv[NCAND_];
#pragma unroll
    for (int t = 0; t < NCAND_; ++t) {
        const float* mrow = mn + (size_t)ci[t] * D_;
        float acc = 0.0f;
#pragma unroll
        for (int j = 0; j < 8; ++j)
            acc = fmaf(x[j], mrow[j * 64 + lane], acc);
#pragma unroll
        for (int off = 32; off; off >>= 1) acc += __shfl_xor(acc, off);
        rv[t] = acc * invn;
    }

    float wv[TOPK_];
    int wi[TOPK_];
    bool used[NCAND_];
#pragma unroll
    for (int t = 0; t < NCAND_; ++t) used[t] = false;
#pragma unroll
    for (int t = 0; t < TOPK_; ++t) {
        float bv = -INFINITY;
        int bi = 0x7fffffff, bu = 0;
#pragma unroll
        for (int u = 0; u < NCAND_; ++u) {
            if (!used[u] && (rv[u] > bv || (rv[u] == bv && ci[u] < bi))) {
                bv = rv[u]; bi = ci[u]; bu = u;
            }
        }
        used[bu] = true;
        wv[t] = bv;
        wi[t] = bi;
    }

    float m = wv[0];
#pragma unroll
    for (int t = 1; t < TOPK_; ++t) m = fmaxf(m, wv[t]);
    float w[TOPK_], ssum = 0.0f;
#pragma unroll
    for (int t = 0; t < TOPK_; ++t) { w[t] = __expf(wv[t] - m); ssum += w[t]; }
    const float scale = rs_ptr[0] / ssum;

    float y[8];
    float s_ = 0.f, ss2 = 0.f;
#pragma unroll
    for (int j = 0; j < 8; ++j) {
        const int d = j * 64 + lane;
        float acc = 0.0f;
#pragma unroll
        for (int t = 0; t < TOPK_; ++t)
            acc += w[t] * mem[(size_t)wi[t] * D_ + d];
        y[j] = x[j] + scale * acc;
        out[(size_t)row * D_ + d] = y[j];
        s_ += y[j];
        ss2 += y[j] * y[j];
    }
#pragma unroll
    for (int off = 32; off; off >>= 1) {
        s_ += __shfl_xor(s_, off);
        ss2 += __shfl_xor(ss2, off);
    }
    const float mu = s_ * (1.0f / D_);
    const float var = ss2 * (1.0f / D_) - mu * mu;
    const float r = rsqrtf(var + LN_EPS_);
#pragma unroll
    for (int j = 0; j < 8; ++j) {
        const int d = j * 64 + lane;
        const float h2 = (y[j] - mu) * r * g2[d] + b2[d];
        unsigned short h16, l16;
        split2(h2, h16, l16);
        h2h[(size_t)row * D_ + d] = h16;
    }
}

// ----------------------------------------------------------------- launch
extern "C" void kernel_launch(void* const* d_in, const int* in_sizes, int n_in,
                              void* d_out, int out_size, void* d_ws, size_t ws_size,
                              hipStream_t stream)
{
    const float* src  = (const float*)d_in[0];
    const float* inw  = (const float*)d_in[1];
    const float* inb  = (const float*)d_in[2];
    const float* outw = (const float*)d_in[3];
    const float* outb = (const float*)d_in[4];
    const float* mem  = (const float*)d_in[5];
    const float* rs   = (const float*)d_in[6];
    const float* ln1g = (const float*)d_in[7];
    const float* ln1b = (const float*)d_in[8];
    const float* ln2g = (const float*)d_in[9];
    const float* ln2b = (const float*)d_in[10];
    const float* w1   = (const float*)d_in[11];
    const float* b1   = (const float*)d_in[12];
    const float* w2   = (const float*)d_in[13];
    const float* b2   = (const float*)d_in[14];
    float* out = (float*)d_out;
    char* ws = (char*)d_ws;
    const size_t MB = 1024ull * 1024ull;

    // fixed region
    float* mn   = (float*)(ws + 0);            // 0-2
    u16* mnh    = (u16*)(ws + 2 * MB);         // 2-3
    u16* mnl    = (u16*)(ws + 3 * MB);         // 3-4
    u16* h2h    = (u16*)(ws + 4 * MB);         // 4-12 [topk .. ffn1]
    u16* inwh   = (u16*)(ws + 4 * MB);         // 4-5.5 [prep .. qkv]
    u16* inwl   = (u16*)(ws + 5 * MB + 512 * 1024);
    u16* outwh  = (u16*)(ws + 7 * MB);         // 7-7.5 [prep .. outproj]
    u16* outwl  = (u16*)(ws + 7 * MB + 512 * 1024);
    u16* w1h    = (u16*)(ws + 77 * MB);        // 77-79
    u16* w2h    = (u16*)(ws + 79 * MB);        // 79-81
    // dynamic
    u16* hh     = (u16*)(ws + 13 * MB);        // 13-21 [prep .. qkv]
    u16* hl     = (u16*)(ws + 21 * MB);        // 21-29
    u16* qkvh   = (u16*)(ws + 29 * MB);        // 29-53 [qkv .. attn]
    u16* qkvl   = (u16*)(ws + 53 * MB);        // 53-77
    u16* ctxh   = (u16*)(ws + 13 * MB);        // 13-21 [attn .. outproj]
    u16* ctxl   = (u16*)(ws + 21 * MB);        // 21-29
    u16* sim16  = (u16*)(ws + 13 * MB);        // 13-29 [sim .. topk] (ctx dead)
    float* src2 = (float*)(ws + 45 * MB);      // 45-61 [outproj .. topk]
    u16* src2h  = (u16*)(ws + 61 * MB);        // 61-69 [outproj .. sim]
    u16* Gbf    = (u16*)(ws + 29 * MB);        // 29-61 [ffn1 .. ffn2] (qkv/sim dead)

    // 0) prep: weight splits + memory normalize + LN1
    prep_kernel<<<dim3(11520), dim3(256), 0, stream>>>(
        inw, outw, w1, w2, mem, src, ln1g, ln1b,
        inwh, inwl, outwh, outwl, w1h, w2h, mn, mnh, mnl, hh, hl);
    // 1) QKV projection
    gemm_mf<3, EP_QKV><<<dim3(64, 12), dim3(256), 0, stream>>>(
        hh, hl, inwh, inwl, inb, nullptr, nullptr, qkvh, qkvl, NTOK_, 1536, 512);
    // 2) attention
    attn_kernel<<<dim3(512), dim3(256), 0, stream>>>(qkvh, qkvl, ctxh, ctxl);
    // 3) out projection + residual
    gemm_mf<3, EP_OUTPROJ><<<dim3(64, 4), dim3(256), 0, stream>>>(
        ctxh, ctxl, outwh, outwl, outb, src, src2, src2h, nullptr, NTOK_, 512, 512);
    // 4) sim = src2 @ mn^T -> bf16 (candidate set only; refined in fp32 in topk)
    gemm_mf<1, EP_SIM><<<dim3(64, 8), dim3(256), 0, stream>>>(
        src2h, nullptr, mnh, nullptr, nullptr, nullptr, nullptr, sim16, nullptr, NTOK_, 1024, 512);
    // 5) topk + retrieval + residual + fused LN2
    topk_kernel<<<dim3(2048), dim3(256), 0, stream>>>(
        sim16, src2, mn, mem, rs, ln2g, ln2b, out, h2h);
    // 6) FFN1 + GELU
    gemm_mf<1, EP_FFN1><<<dim3(64, 16), dim3(256), 0, stream>>>(
        h2h, nullptr, w1h, nullptr, b1, nullptr, nullptr, Gbf, nullptr, NTOK_, 2048, 512);
    // 7) FFN2 + bias + residual
    gemm_mf<1, EP_FFN2><<<dim3(64, 4), dim3(256), 0, stream>>>(
        Gbf, nullptr, w2h, nullptr, b2, out, out, nullptr, nullptr, NTOK_, 512, 2048);
}

// Round 15
// 277.340 us; speedup vs baseline: 1.0264x; 1.0264x over previous
//
#include <hip/hip_runtime.h>
#include <math.h>

#define D_ 512
#define H_ 8
#define DFF_ 2048
#define SLOTS_ 1024
#define TOPK_ 5
#define NCAND_ 8
#define NTOK_ 8192
#define SEQ_ 1024
#define LN_EPS_ 1e-5f

typedef __attribute__((ext_vector_type(8))) short bf16x8;
typedef __attribute__((ext_vector_type(4))) float f32x4;
typedef __attribute__((ext_vector_type(4))) unsigned u32x4;
typedef unsigned short u16;

// split fp32 -> bf16 hi + bf16 lo (truncation; rem captured to ~2^-16 rel)
__device__ inline void split2(float x, unsigned short& hi, unsigned short& lo) {
    unsigned u = __builtin_bit_cast(unsigned, x);
    hi = (unsigned short)(u >> 16);
    float h = __builtin_bit_cast(float, u & 0xFFFF0000u);
    float rem = x - h;
    lo = (unsigned short)(__builtin_bit_cast(unsigned, rem) >> 16);
}

__device__ __forceinline__ void gld16(const void* g, void* l) {
    __builtin_amdgcn_global_load_lds(
        (const __attribute__((address_space(1))) void*)g,
        (__attribute__((address_space(3))) void*)l, 16, 0, 0);
}

__device__ __forceinline__ int SW7(int r) { return (r ^ (r >> 3)) & 7; }
__device__ __forceinline__ const bf16x8* frag(const unsigned short* p, int r, int c) {
    return (const bf16x8*)(p + r * 64 + ((c ^ SW7(r)) << 3));
}

// ---------------------------------------------------------------- prep: weight splits + mn + LN1
__global__ __launch_bounds__(256) void prep_kernel(
    const float* __restrict__ inw, const float* __restrict__ outw,
    const float* __restrict__ w1, const float* __restrict__ w2,
    const float* __restrict__ mem, const float* __restrict__ src,
    const float* __restrict__ ln1g, const float* __restrict__ ln1b,
    u16* __restrict__ inwh, u16* __restrict__ inwl,
    u16* __restrict__ outwh, u16* __restrict__ outwl,
    u16* __restrict__ w1h, u16* __restrict__ w2h,
    float* __restrict__ mn, u16* __restrict__ mnh, u16* __restrict__ mnl,
    u16* __restrict__ hh, u16* __restrict__ hl)
{
    const int bid = blockIdx.x;
    const int t = threadIdx.x;
    if (bid < 3072) {
        const int i = (bid * 256 + t) * 4;
        const float* x;
        u16 *hhp, *llp;
        int base;
        if (i < 786432)       { x = inw;  hhp = inwh;  llp = inwl;  base = 0; }
        else if (i < 1048576) { x = outw; hhp = outwh; llp = outwl; base = 786432; }
        else if (i < 2097152) { x = w1;   hhp = w1h;   llp = nullptr; base = 1048576; }
        else                  { x = w2;   hhp = w2h;   llp = nullptr; base = 2097152; }
        const int j = i - base;
        const float4 v = *(const float4*)(x + j);
        const float vv[4] = {v.x, v.y, v.z, v.w};
        u16 h[4], l[4];
#pragma unroll
        for (int e = 0; e < 4; ++e) split2(vv[e], h[e], l[e]);
        hhp[j + 0] = h[0]; hhp[j + 1] = h[1]; hhp[j + 2] = h[2]; hhp[j + 3] = h[3];
        if (llp) { llp[j + 0] = l[0]; llp[j + 1] = l[1]; llp[j + 2] = l[2]; llp[j + 3] = l[3]; }
    } else if (bid < 3328) {
        const int row = (bid - 3072) * 4 + (t >> 6);
        const int lane = t & 63;
        float v[8];
        float ss = 0.0f;
#pragma unroll
        for (int j = 0; j < 8; ++j) {
            v[j] = mem[(size_t)row * D_ + j * 64 + lane];
            ss += v[j] * v[j];
        }
#pragma unroll
        for (int off = 32; off; off >>= 1) ss += __shfl_xor(ss, off);
        const float inv = 1.0f / fmaxf(sqrtf(ss), 1e-12f);
#pragma unroll
        for (int j = 0; j < 8; ++j) {
            const float y = v[j] * inv;
            mn[(size_t)row * D_ + j * 64 + lane] = y;
            u16 h, l;
            split2(y, h, l);
            mnh[(size_t)row * D_ + j * 64 + lane] = h;
            mnl[(size_t)row * D_ + j * 64 + lane] = l;
        }
    } else {
        const int row = bid - 3328;
        const float a = src[(size_t)row * D_ + t];
        const float b = src[(size_t)row * D_ + t + 256];
        float s = a + b;
        float ss = a * a + b * b;
#pragma unroll
        for (int off = 32; off; off >>= 1) {
            s += __shfl_xor(s, off);
            ss += __shfl_xor(ss, off);
        }
        __shared__ float rs[4], rss[4];
        if ((t & 63) == 0) { rs[t >> 6] = s; rss[t >> 6] = ss; }
        __syncthreads();
        s = rs[0] + rs[1] + rs[2] + rs[3];
        ss = rss[0] + rss[1] + rss[2] + rss[3];
        const float mu = s * (1.0f / D_);
        const float var = ss * (1.0f / D_) - mu * mu;
        const float r = rsqrtf(var + LN_EPS_);
        const float y0 = (a - mu) * r * ln1g[t] + ln1b[t];
        const float y1 = (b - mu) * r * ln1g[t + 256] + ln1b[t + 256];
        u16 h0, l0, h1, l1;
        split2(y0, h0, l0);
        split2(y1, h1, l1);
        hh[(size_t)row * D_ + t] = h0;
        hh[(size_t)row * D_ + t + 256] = h1;
        hl[(size_t)row * D_ + t] = l0;
        hl[(size_t)row * D_ + t + 256] = l1;
    }
}

// ------------------------------------------------- MFMA GEMM (NT), 128x128 tile
enum { EP_QKV = 0, EP_OUTPROJ = 1, EP_SIM = 2, EP_FFN1 = 3, EP_FFN2 = 4 };

template <int SPLIT, int MODE>
__global__ __launch_bounds__(256) void gemm_mf(
    const unsigned short* __restrict__ Ahg, const unsigned short* __restrict__ Alg,
    const unsigned short* __restrict__ Bhg, const unsigned short* __restrict__ Blg,
    const float* __restrict__ bias, const float* __restrict__ res,
    float* __restrict__ C,
    unsigned short* __restrict__ Ch, unsigned short* __restrict__ Cl,
    int M, int N, int K)
{
    __shared__ __align__(16) unsigned short sm[(SPLIT == 3 ? 4 : 2) * 8192];
    unsigned short* Ah = sm;
    unsigned short* Al = sm + 8192;
    unsigned short* Bh = sm + (SPLIT == 3 ? 16384 : 8192);
    unsigned short* Bl = sm + 24576;

    const int tid = threadIdx.x;
    const int lane = tid & 63;
    const int w = tid >> 6;
    const int wr = w >> 1, wc = w & 1;
    const int g = lane >> 4, ln = lane & 15;
    const int m0 = blockIdx.x * 128, n0 = blockIdx.y * 128;
    const int lrow8 = lane >> 3, lchunk = lane & 7;

    const unsigned short* gsrc;
    unsigned short* lds;
    int rbase, rofs, nblk;
    if (SPLIT == 3) {
        nblk = 16; rofs = 0;
        if (w == 0)      { gsrc = Ahg; lds = Ah; rbase = m0; }
        else if (w == 1) { gsrc = Alg; lds = Al; rbase = m0; }
        else if (w == 2) { gsrc = Bhg; lds = Bh; rbase = n0; }
        else             { gsrc = Blg; lds = Bl; rbase = n0; }
    } else {
        nblk = 8; rofs = (w & 1) * 64;
        if (w < 2) { gsrc = Ahg; lds = Ah; rbase = m0; }
        else       { gsrc = Bhg; lds = Bh; rbase = n0; }
    }

    f32x4 acc[4][4];
#pragma unroll
    for (int i = 0; i < 4; ++i)
#pragma unroll
        for (int j = 0; j < 4; ++j) acc[i][j] = (f32x4){0.f, 0.f, 0.f, 0.f};

    for (int k0 = 0; k0 < K; k0 += 64) {
#pragma unroll
        for (int blk = 0; blk < nblk; ++blk) {
            const int row = rofs + blk * 8 + lrow8;
            const int sc = lchunk ^ SW7(row);
            gld16(gsrc + (size_t)(rbase + row) * K + k0 + sc * 8,
                  lds + (rofs + blk * 8) * 64);
        }
        __syncthreads();

#pragma unroll
        for (int ks = 0; ks < 2; ++ks) {
            bf16x8 a_h[4], a_l[4], b_h[4], b_l[4];
#pragma unroll
            for (int mi = 0; mi < 4; ++mi) {
                a_h[mi] = *frag(Ah, wr * 64 + mi * 16 + ln, ks * 4 + g);
                if (SPLIT == 3) a_l[mi] = *frag(Al, wr * 64 + mi * 16 + ln, ks * 4 + g);
            }
#pragma unroll
            for (int ni = 0; ni < 4; ++ni) {
                b_h[ni] = *frag(Bh, wc * 64 + ni * 16 + ln, ks * 4 + g);
                if (SPLIT == 3) b_l[ni] = *frag(Bl, wc * 64 + ni * 16 + ln, ks * 4 + g);
            }
#pragma unroll
            for (int mi = 0; mi < 4; ++mi)
#pragma unroll
                for (int ni = 0; ni < 4; ++ni) {
                    acc[mi][ni] = __builtin_amdgcn_mfma_f32_16x16x32_bf16(
                        a_h[mi], b_h[ni], acc[mi][ni], 0, 0, 0);
                    if (SPLIT == 3) {
                        acc[mi][ni] = __builtin_amdgcn_mfma_f32_16x16x32_bf16(
                            a_h[mi], b_l[ni], acc[mi][ni], 0, 0, 0);
                        acc[mi][ni] = __builtin_amdgcn_mfma_f32_16x16x32_bf16(
                            a_l[mi], b_h[ni], acc[mi][ni], 0, 0, 0);
                    }
                }
        }
        __syncthreads();
    }

#pragma unroll
    for (int mi = 0; mi < 4; ++mi) {
#pragma unroll
        for (int ni = 0; ni < 4; ++ni) {
            const int gn = n0 + wc * 64 + ni * 16 + ln;
            const float bz = (MODE == EP_SIM) ? 0.0f : bias[gn];
#pragma unroll
            for (int r2 = 0; r2 < 4; ++r2) {
                const int gm = m0 + wr * 64 + mi * 16 + g * 4 + r2;
                float v = acc[mi][ni][r2];
                if (MODE == EP_SIM) {
                    unsigned short h16, l16;
                    split2(v, h16, l16);
                    Ch[(size_t)gm * N + gn] = h16;
                } else if (MODE == EP_QKV) {
                    v += bz;
                    if (gn < D_) v *= 0.125f;     // fold 1/sqrt(DH) into Q
                    unsigned short h16, l16;
                    split2(v, h16, l16);
                    Ch[(size_t)gm * N + gn] = h16;
                    Cl[(size_t)gm * N + gn] = l16;
                } else if (MODE == EP_OUTPROJ) {
                    v += bz + res[(size_t)gm * N + gn];
                    C[(size_t)gm * N + gn] = v;
                    unsigned short h16, l16;
                    split2(v, h16, l16);
                    Ch[(size_t)gm * N + gn] = h16;
                } else if (MODE == EP_FFN1) {
                    v += bz;
                    v = 0.5f * v * (1.0f + erff(v * 0.70710678118654752f));
                    unsigned short h16, l16;
                    split2(v, h16, l16);
                    Ch[(size_t)gm * N + gn] = h16;
                } else {   // EP_FFN2
                    v += bz + res[(size_t)gm * N + gn];
                    C[(size_t)gm * N + gn] = v;
                }
            }
        }
    }
}

// ------------------------------------------------- flash attention, MFMA bf16x3
__global__ __launch_bounds__(256, 2) void attn_kernel(
    const unsigned short* __restrict__ qkvh, const unsigned short* __restrict__ qkvl,
    unsigned short* __restrict__ ctxh, unsigned short* __restrict__ ctxl)
{
    const int id = blockIdx.x;          // 0..511
    const int bh = id & 63;
    const int qt = id >> 6;             // 0..7
    const int b = bh >> 3, h = bh & 7;
    const int tok0 = b * SEQ_ + qt * 128;
    const int kbase0 = b * SEQ_;
    const int tid = threadIdx.x;
    const int lane = tid & 63;
    const int w = tid >> 6;             // wave: 32 q-rows
    const int ln = lane & 15, g = lane >> 4;
    const int lrow8 = lane >> 3, lchunk = lane & 7;

    __shared__ __align__(16) unsigned char smb[65536];
    unsigned*       PP  = (unsigned*)smb;
    unsigned short* Qh  = (unsigned short*)smb;
    unsigned short* Ql  = (unsigned short*)(smb + 16384);
    unsigned short* Kh  = (unsigned short*)(smb + 32768);
    unsigned short* Kl  = (unsigned short*)(smb + 40960);
    unsigned short* Vth = (unsigned short*)(smb + 49152);
    unsigned short* Vtl = (unsigned short*)(smb + 57344);

    const int qoff = h * 64, koff = 512 + h * 64, voff = 1024 + h * 64;

    // ---- stage Q (pre-scaled), hoist fragments
#pragma unroll
    for (int blk = 0; blk < 4; ++blk) {
        const int row = w * 32 + blk * 8 + lrow8;
        const int sc = lchunk ^ SW7(row);
        gld16(qkvh + (size_t)(tok0 + row) * 1536 + qoff + sc * 8,
              Qh + (w * 32 + blk * 8) * 64);
        gld16(qkvl + (size_t)(tok0 + row) * 1536 + qoff + sc * 8,
              Ql + (w * 32 + blk * 8) * 64);
    }
    __syncthreads();
    bf16x8 qfh[2][2], qfl[2][2];
#pragma unroll
    for (int qi = 0; qi < 2; ++qi)
#pragma unroll
        for (int ks = 0; ks < 2; ++ks) {
            qfh[qi][ks] = *frag(Qh, w * 32 + qi * 16 + ln, ks * 4 + g);
            qfl[qi][ks] = *frag(Ql, w * 32 + qi * 16 + ln, ks * 4 + g);
        }
    __syncthreads();   // Q reads done before PP reused for P

    f32x4 o[4][2];      // O^T[d-tile di][q-tile qi]
#pragma unroll
    for (int di = 0; di < 4; ++di)
#pragma unroll
        for (int qi = 0; qi < 2; ++qi) o[di][qi] = (f32x4){0.f, 0.f, 0.f, 0.f};
    float mrow2[2] = {-INFINITY, -INFINITY};
    float lrow2[2] = {0.f, 0.f};

    // V staging partition: consecutive lanes -> consecutive d-chunks (coalesced)
    const int dc = tid & 7, p2 = tid >> 3;

    for (int kt = 0; kt < 16; ++kt) {
        const int kb2 = kbase0 + kt * 64;
        // ---- stage K
#pragma unroll
        for (int blk = 0; blk < 2; ++blk) {
            const int row = w * 16 + blk * 8 + lrow8;
            const int sc = lchunk ^ SW7(row);
            gld16(qkvh + (size_t)(kb2 + row) * 1536 + koff + sc * 8,
                  Kh + (w * 16 + blk * 8) * 64);
            gld16(qkvl + (size_t)(kb2 + row) * 1536 + koff + sc * 8,
                  Kl + (w * 16 + blk * 8) * 64);
        }
        // ---- stage V transposed (swizzled, packed b32)
        {
            const size_t b0 = (size_t)(kb2 + 2 * p2) * 1536 + voff + dc * 8;
            const bf16x8 h0 = *(const bf16x8*)(qkvh + b0);
            const bf16x8 h1 = *(const bf16x8*)(qkvh + b0 + 1536);
            const bf16x8 l0 = *(const bf16x8*)(qkvl + b0);
            const bf16x8 l1 = *(const bf16x8*)(qkvl + b0 + 1536);
#pragma unroll
            for (int j = 0; j < 8; ++j) {
                const int d = dc * 8 + j;
                const int idx = d * 64 + (((p2 >> 2) ^ SW7(d)) << 3) + ((p2 & 3) << 1);
                *(unsigned*)&Vth[idx] = (unsigned)(unsigned short)h0[j]
                                      | ((unsigned)(unsigned short)h1[j] << 16);
                *(unsigned*)&Vtl[idx] = (unsigned)(unsigned short)l0[j]
                                      | ((unsigned)(unsigned short)l1[j] << 16);
            }
        }
        __syncthreads();

        // ---- S^T = K Q^T (bf16x3): s[ki][qi], row=k (g*4+r2), col=q (ln)
        f32x4 s[4][2];
#pragma unroll
        for (int ki = 0; ki < 4; ++ki)
#pragma unroll
            for (int qi = 0; qi < 2; ++qi) s[ki][qi] = (f32x4){0.f, 0.f, 0.f, 0.f};
        __builtin_amdgcn_s_setprio(1);
#pragma unroll
        for (int ks = 0; ks < 2; ++ks) {
            bf16x8 kbh[4], kbl[4];
#pragma unroll
            for (int ki = 0; ki < 4; ++ki) {
                kbh[ki] = *frag(Kh, ki * 16 + ln, ks * 4 + g);
                kbl[ki] = *frag(Kl, ki * 16 + ln, ks * 4 + g);
            }
#pragma unroll
            for (int ki = 0; ki < 4; ++ki)
#pragma unroll
                for (int qi = 0; qi < 2; ++qi) {
                    s[ki][qi] = __builtin_amdgcn_mfma_f32_16x16x32_bf16(kbh[ki], qfh[qi][ks], s[ki][qi], 0, 0, 0);
                    s[ki][qi] = __builtin_amdgcn_mfma_f32_16x16x32_bf16(kbh[ki], qfl[qi][ks], s[ki][qi], 0, 0, 0);
                    s[ki][qi] = __builtin_amdgcn_mfma_f32_16x16x32_bf16(kbl[ki], qfh[qi][ks], s[ki][qi], 0, 0, 0);
                }
        }
        __builtin_amdgcn_s_setprio(0);

        // ---- online softmax: lane holds 16 k-values per qi for query q=qi*16+ln
        float tm2[2], alpha2[2], psum2[2];
#pragma unroll
        for (int qi = 0; qi < 2; ++qi) {
            float m01 = fmaxf(fmaxf(s[0][qi][0], s[0][qi][1]), fmaxf(s[0][qi][2], s[0][qi][3]));
            float m23 = fmaxf(fmaxf(s[1][qi][0], s[1][qi][1]), fmaxf(s[1][qi][2], s[1][qi][3]));
            float m45 = fmaxf(fmaxf(s[2][qi][0], s[2][qi][1]), fmaxf(s[2][qi][2], s[2][qi][3]));
            float m67 = fmaxf(fmaxf(s[3][qi][0], s[3][qi][1]), fmaxf(s[3][qi][2], s[3][qi][3]));
            tm2[qi] = fmaxf(fmaxf(m01, m23), fmaxf(m45, m67));
        }
#pragma unroll
        for (int qi = 0; qi < 2; ++qi) {
            tm2[qi] = fmaxf(tm2[qi], __shfl_xor(tm2[qi], 16));
            tm2[qi] = fmaxf(tm2[qi], __shfl_xor(tm2[qi], 32));
            const float mnew = fmaxf(mrow2[qi], tm2[qi]);
            alpha2[qi] = __expf(mrow2[qi] - mnew);
            mrow2[qi] = mnew;
            psum2[qi] = 0.f;
        }
        // P = exp(S^T - m): pack (h|l<<16); chunk (ki*4+g) ^ (ln&7) -> conflict-free
#pragma unroll
        for (int qi = 0; qi < 2; ++qi)
#pragma unroll
            for (int ki = 0; ki < 4; ++ki) {
                u32x4 pv;
#pragma unroll
                for (int r2 = 0; r2 < 4; ++r2) {
                    const float p = __expf(s[ki][qi][r2] - mrow2[qi]);
                    psum2[qi] += p;
                    unsigned short h16, l16;
                    split2(p, h16, l16);
                    pv[r2] = (unsigned)h16 | ((unsigned)l16 << 16);
                }
                *(u32x4*)&PP[(w * 32 + qi * 16 + ln) * 64 + (((ki * 4 + g) ^ (ln & 7)) << 2)] = pv;
            }
#pragma unroll
        for (int qi = 0; qi < 2; ++qi) {
            psum2[qi] += __shfl_xor(psum2[qi], 16);
            psum2[qi] += __shfl_xor(psum2[qi], 32);
            lrow2[qi] = lrow2[qi] * alpha2[qi] + psum2[qi];
        }
#pragma unroll
        for (int di = 0; di < 4; ++di)
#pragma unroll
            for (int qi = 0; qi < 2; ++qi)
#pragma unroll
                for (int r2 = 0; r2 < 4; ++r2)
                    o[di][qi][r2] *= alpha2[qi];

        // ---- O^T += Vt P^T (bf16x3)
        __builtin_amdgcn_s_setprio(1);
#pragma unroll
        for (int ks = 0; ks < 2; ++ks) {
            bf16x8 pah[2], pal[2];
#pragma unroll
            for (int qi = 0; qi < 2; ++qi) {
                const unsigned* rowp = PP + (w * 32 + qi * 16 + ln) * 64;
                const int c0 = (2 * ks + (g >> 1)) * 4 + (g & 1) * 2;
                const u32x4 q0 = *(const u32x4*)(rowp + (((c0    ) ^ (ln & 7)) << 2));
                const u32x4 q1 = *(const u32x4*)(rowp + (((c0 + 1) ^ (ln & 7)) << 2));
                u32x4 hu, lu;
                hu[0] = __builtin_amdgcn_perm(q0[1], q0[0], 0x05040100u);
                hu[1] = __builtin_amdgcn_perm(q0[3], q0[2], 0x05040100u);
                hu[2] = __builtin_amdgcn_perm(q1[1], q1[0], 0x05040100u);
                hu[3] = __builtin_amdgcn_perm(q1[3], q1[2], 0x05040100u);
                lu[0] = __builtin_amdgcn_perm(q0[1], q0[0], 0x07060302u);
                lu[1] = __builtin_amdgcn_perm(q0[3], q0[2], 0x07060302u);
                lu[2] = __builtin_amdgcn_perm(q1[1], q1[0], 0x07060302u);
                lu[3] = __builtin_amdgcn_perm(q1[3], q1[2], 0x07060302u);
                pah[qi] = __builtin_bit_cast(bf16x8, hu);
                pal[qi] = __builtin_bit_cast(bf16x8, lu);
            }
            bf16x8 vbh[4], vbl[4];
#pragma unroll
            for (int di = 0; di < 4; ++di) {
                vbh[di] = *frag(Vth, di * 16 + ln, ks * 4 + g);
                vbl[di] = *frag(Vtl, di * 16 + ln, ks * 4 + g);
            }
#pragma unroll
            for (int di = 0; di < 4; ++di)
#pragma unroll
                for (int qi = 0; qi < 2; ++qi) {
                    o[di][qi] = __builtin_amdgcn_mfma_f32_16x16x32_bf16(vbh[di], pah[qi], o[di][qi], 0, 0, 0);
                    o[di][qi] = __builtin_amdgcn_mfma_f32_16x16x32_bf16(vbh[di], pal[qi], o[di][qi], 0, 0, 0);
                    o[di][qi] = __builtin_amdgcn_mfma_f32_16x16x32_bf16(vbl[di], pah[qi], o[di][qi], 0, 0, 0);
                }
        }
        __builtin_amdgcn_s_setprio(0);
        __syncthreads();   // PV done before next staging overwrites K/V
    }

    // ---- epilogue: O^T -> wave-private LDS transpose (reuse PP) -> coalesced stores
#pragma unroll
    for (int di = 0; di < 4; ++di)
#pragma unroll
        for (int qi = 0; qi < 2; ++qi) {
            const float inv = 1.0f / lrow2[qi];
            u32x4 tv;
#pragma unroll
            for (int r2 = 0; r2 < 4; ++r2) {
                const float v = o[di][qi][r2] * inv;
                unsigned short h16, l16;
                split2(v, h16, l16);
                tv[r2] = (unsigned)h16 | ((unsigned)l16 << 16);
            }
            *(u32x4*)&PP[(w * 32 + qi * 16 + ln) * 64 + (((di * 4 + g) ^ (ln & 7)) << 2)] = tv;
        }
    __syncthreads();
    {
        const int qrow = lane >> 1, halfd = lane & 1;
        const unsigned* rowp = PP + (w * 32 + qrow) * 64;
        const size_t gbase = (size_t)(tok0 + w * 32 + qrow) * D_ + h * 64;
#pragma unroll
        for (int gi = 0; gi < 2; ++gi) {
            const int di = halfd * 2 + gi;
#pragma unroll
            for (int pr = 0; pr < 2; ++pr) {
                const int c = di * 4 + pr * 2;
                const u32x4 t0 = *(const u32x4*)(rowp + (((c    ) ^ (qrow & 7)) << 2));
                const u32x4 t1 = *(const u32x4*)(rowp + (((c + 1) ^ (qrow & 7)) << 2));
                u32x4 hv, lv;
                hv[0] = __builtin_amdgcn_perm(t0[1], t0[0], 0x05040100u);
                hv[1] = __builtin_amdgcn_perm(t0[3], t0[2], 0x05040100u);
                hv[2] = __builtin_amdgcn_perm(t1[1], t1[0], 0x05040100u);
                hv[3] = __builtin_amdgcn_perm(t1[3], t1[2], 0x05040100u);
                lv[0] = __builtin_amdgcn_perm(t0[1], t0[0], 0x07060302u);
                lv[1] = __builtin_amdgcn_perm(t0[3], t0[2], 0x07060302u);
                lv[2] = __builtin_amdgcn_perm(t1[1], t1[0], 0x07060302u);
                lv[3] = __builtin_amdgcn_perm(t1[3], t1[2], 0x07060302u);
                *(u32x4*)(ctxh + gbase + di * 16 + pr * 8) = hv;
                *(u32x4*)(ctxl + gbase + di * 16 + pr * 8) = lv;
            }
        }
    }
}

// ---- top-8 -> fp32 refine -> top-5 + softmax + gather + residual + fused LN2
__global__ __launch_bounds__(256) void topk_kernel(
    const u16* __restrict__ sim, const float* __restrict__ src2,
    const float* __restrict__ mn, const float* __restrict__ mem,
    const float* __restrict__ rs_ptr, const float* __restrict__ g2,
    const float* __restrict__ b2, float* __restrict__ out,
    unsigned short* __restrict__ h2h)
{
    const int row = blockIdx.x * 4 + (threadIdx.x >> 6);
    const int lane = threadIdx.x & 63;
    float v[16];
#pragma unroll
    for (int j = 0; j < 16; ++j) {
        const unsigned sv = sim[(size_t)row * SLOTS_ + j * 64 + lane];
        v[j] = __builtin_bit_cast(float, sv << 16);
    }

    int ci[NCAND_];
#pragma unroll
    for (int t = 0; t < NCAND_; ++t) {
        float bv = -INFINITY;
        int bi = 0x7fffffff;
#pragma unroll
        for (int j = 0; j < 16; ++j) {
            const int idx = j * 64 + lane;
            if (v[j] > bv) { bv = v[j]; bi = idx; }
        }
#pragma unroll
        for (int off = 32; off; off >>= 1) {
            const float ov = __shfl_xor(bv, off);
            const int oi = __shfl_xor(bi, off);
            if (ov > bv || (ov == bv && oi < bi)) { bv = ov; bi = oi; }
        }
        ci[t] = bi;
#pragma unroll
        for (int j = 0; j < 16; ++j)
            if (j * 64 + lane == bi) v[j] = -INFINITY;
    }

    float x[8];
    float ss = 0.0f;
#pragma unroll
    for (int j = 0; j < 8; ++j) {
        x[j] = src2[(size_t)row * D_ + j * 64 + lane];
        ss += x[j] * x[j];
    }
#pragma unroll
    for (int off = 32; off; off >>= 1) ss += __shfl_xor(ss, off);
    const float invn = 1.0f / fmaxf(sqrtf(ss), 1e-12f);

    float rv[NCAND_];
#pragma unroll
    for (int t = 0; t < NCAND_; ++t) {
        const float* mrow = mn + (size_t)ci[t] * D_;
        float acc = 0.0f;
#pragma unroll
        for (int j = 0; j < 8; ++j)
            acc = fmaf(x[j], mrow[j * 64 + lane], acc);
#pragma unroll
        for (int off = 32; off; off >>= 1) acc += __shfl_xor(acc, off);
        rv[t] = acc * invn;
    }

    float wv[TOPK_];
    int wi[TOPK_];
    bool used[NCAND_];
#pragma unroll
    for (int t = 0; t < NCAND_; ++t) used[t] = false;
#pragma unroll
    for (int t = 0; t < TOPK_; ++t) {
        float bv = -INFINITY;
        int bi = 0x7fffffff, bu = 0;
#pragma unroll
        for (int u = 0; u < NCAND_; ++u) {
            if (!used[u] && (rv[u] > bv || (rv[u] == bv && ci[u] < bi))) {
                bv = rv[u]; bi = ci[u]; bu = u;
            }
        }
        used[bu] = true;
        wv[t] = bv;
        wi[t] = bi;
    }

    float m = wv[0];
#pragma unroll
    for (int t = 1; t < TOPK_; ++t) m = fmaxf(m, wv[t]);
    float w[TOPK_], ssum = 0.0f;
#pragma unroll
    for (int t = 0; t < TOPK_; ++t) { w[t] = __expf(wv[t] - m); ssum += w[t]; }
    const float scale = rs_ptr[0] / ssum;

    float y[8];
    float s_ = 0.f, ss2 = 0.f;
#pragma unroll
    for (int j = 0; j < 8; ++j) {
        const int d = j * 64 + lane;
        float acc = 0.0f;
#pragma unroll
        for (int t = 0; t < TOPK_; ++t)
            acc += w[t] * mem[(size_t)wi[t] * D_ + d];
        y[j] = x[j] + scale * acc;
        out[(size_t)row * D_ + d] = y[j];
        s_ += y[j];
        ss2 += y[j] * y[j];
    }
#pragma unroll
    for (int off = 32; off; off >>= 1) {
        s_ += __shfl_xor(s_, off);
        ss2 += __shfl_xor(ss2, off);
    }
    const float mu = s_ * (1.0f / D_);
    const float var = ss2 * (1.0f / D_) - mu * mu;
    const float r = rsqrtf(var + LN_EPS_);
#pragma unroll
    for (int j = 0; j < 8; ++j) {
        const int d = j * 64 + lane;
        const float h2 = (y[j] - mu) * r * g2[d] + b2[d];
        unsigned short h16, l16;
        split2(h2, h16, l16);
        h2h[(size_t)row * D_ + d] = h16;
    }
}

// ----------------------------------------------------------------- launch
extern "C" void kernel_launch(void* const* d_in, const int* in_sizes, int n_in,
                              void* d_out, int out_size, void* d_ws, size_t ws_size,
                              hipStream_t stream)
{
    const float* src  = (const float*)d_in[0];
    const float* inw  = (const float*)d_in[1];
    const float* inb  = (const float*)d_in[2];
    const float* outw = (const float*)d_in[3];
    const float* outb = (const float*)d_in[4];
    const float* mem  = (const float*)d_in[5];
    const float* rs   = (const float*)d_in[6];
    const float* ln1g = (const float*)d_in[7];
    const float* ln1b = (const float*)d_in[8];
    const float* ln2g = (const float*)d_in[9];
    const float* ln2b = (const float*)d_in[10];
    const float* w1   = (const float*)d_in[11];
    const float* b1   = (const float*)d_in[12];
    const float* w2   = (const float*)d_in[13];
    const float* b2   = (const float*)d_in[14];
    float* out = (float*)d_out;
    char* ws = (char*)d_ws;
    const size_t MB = 1024ull * 1024ull;

    // fixed region
    float* mn   = (float*)(ws + 0);            // 0-2
    u16* mnh    = (u16*)(ws + 2 * MB);         // 2-3
    u16* mnl    = (u16*)(ws + 3 * MB);         // 3-4
    u16* h2h    = (u16*)(ws + 4 * MB);         // 4-12 [topk .. ffn1]
    u16* inwh   = (u16*)(ws + 4 * MB);         // 4-5.5 [prep .. qkv]
    u16* inwl   = (u16*)(ws + 5 * MB + 512 * 1024);
    u16* outwh  = (u16*)(ws + 7 * MB);         // 7-7.5 [prep .. outproj]
    u16* outwl  = (u16*)(ws + 7 * MB + 512 * 1024);
    u16* w1h    = (u16*)(ws + 77 * MB);        // 77-79
    u16* w2h    = (u16*)(ws + 79 * MB);        // 79-81
    // dynamic
    u16* hh     = (u16*)(ws + 13 * MB);        // 13-21 [prep .. qkv]
    u16* hl     = (u16*)(ws + 21 * MB);        // 21-29
    u16* qkvh   = (u16*)(ws + 29 * MB);        // 29-53 [qkv .. attn]
    u16* qkvl   = (u16*)(ws + 53 * MB);        // 53-77
    u16* ctxh   = (u16*)(ws + 13 * MB);        // 13-21 [attn .. outproj]
    u16* ctxl   = (u16*)(ws + 21 * MB);        // 21-29
    u16* sim16  = (u16*)(ws + 13 * MB);        // 13-29 [sim .. topk] (ctx dead)
    float* src2 = (float*)(ws + 45 * MB);      // 45-61 [outproj .. topk]
    u16* src2h  = (u16*)(ws + 61 * MB);        // 61-69 [outproj .. sim]
    u16* Gbf    = (u16*)(ws + 29 * MB);        // 29-61 [ffn1 .. ffn2] (qkv/sim dead)

    // 0) prep: weight splits + memory normalize + LN1
    prep_kernel<<<dim3(11520), dim3(256), 0, stream>>>(
        inw, outw, w1, w2, mem, src, ln1g, ln1b,
        inwh, inwl, outwh, outwl, w1h, w2h, mn, mnh, mnl, hh, hl);
    // 1) QKV projection
    gemm_mf<3, EP_QKV><<<dim3(64, 12), dim3(256), 0, stream>>>(
        hh, hl, inwh, inwl, inb, nullptr, nullptr, qkvh, qkvl, NTOK_, 1536, 512);
    // 2) attention
    attn_kernel<<<dim3(512), dim3(256), 0, stream>>>(qkvh, qkvl, ctxh, ctxl);
    // 3) out projection + residual
    gemm_mf<3, EP_OUTPROJ><<<dim3(64, 4), dim3(256), 0, stream>>>(
        ctxh, ctxl, outwh, outwl, outb, src, src2, src2h, nullptr, NTOK_, 512, 512);
    // 4) sim = src2 @ mn^T -> bf16 (candidate set only; refined in fp32 in topk)
    gemm_mf<1, EP_SIM><<<dim3(64, 8), dim3(256), 0, stream>>>(
        src2h, nullptr, mnh, nullptr, nullptr, nullptr, nullptr, sim16, nullptr, NTOK_, 1024, 512);
    // 5) topk + retrieval + residual + fused LN2
    topk_kernel<<<dim3(2048), dim3(256), 0, stream>>>(
        sim16, src2, mn, mem, rs, ln2g, ln2b, out, h2h);
    // 6) FFN1 + GELU
    gemm_mf<1, EP_FFN1><<<dim3(64, 16), dim3(256), 0, stream>>>(
        h2h, nullptr, w1h, nullptr, b1, nullptr, nullptr, Gbf, nullptr, NTOK_, 2048, 512);
    // 7) FFN2 + bias + residual
    gemm_mf<1, EP_FFN2><<<dim3(64, 4), dim3(256), 0, stream>>>(
        Gbf, nullptr, w2h, nullptr, b2, out, out, nullptr, nullptr, NTOK_, 512, 2048);
}